// Round 16
// baseline (42.599 us; speedup 1.0000x reference)
//
#include <hip/hip_runtime.h>
#include <hip/hip_bf16.h>
#include <hip/hip_fp16.h>

typedef _Float16 half8 __attribute__((ext_vector_type(8)));
typedef _Float16 half2v __attribute__((ext_vector_type(2)));
typedef float f32x4 __attribute__((ext_vector_type(4)));

#define B_ 4
#define C_ 64
#define O_ 64
#define H_ 128
#define W_ 128
#define HT 8     // tile rows
#define WT 16    // tile cols
#define HALO 3
#define RS 14    // staged rows (HT + 2*HALO)
#define CS 22    // staged cols (WT + 2*HALO)
// xs layout: [pixel][ch], pixel stride 72 f16 = 144B = 9 half8/uint4 slots

__device__ __forceinline__ unsigned pkh(float lo, float hi) {
  half2v v = {(_Float16)lo, (_Float16)hi};
  return __builtin_bit_cast(unsigned, v);
}

// ---------------------------------------------------------------------------
// Kernel 0: pre-build fragment-ready f16 weights in workspace.
//  wf  (deform_w): 18 k-steps x 4 o-tiles x 64 lanes x 8 = 36864 f16
//  wfm (mask_w padded to 16 rows): 18 k-steps x 64 lanes x 8 = 9216 f16
// ---------------------------------------------------------------------------
__global__ void build_frags(const float* __restrict__ dw,
                            const float* __restrict__ mw,
                            _Float16* __restrict__ wsb) {
  int t = blockIdx.x * 256 + threadIdx.x;
  if (t < 36864) {
    int j = t & 7, lane = (t >> 3) & 63, ot = (t >> 9) & 3, s = t >> 11;
    int kk = s >> 1, ch = s & 1;
    int o = ot * 16 + (lane & 15);
    int c = ch * 32 + ((lane >> 4) << 3) + j;
    wsb[t] = (_Float16)dw[(o * 64 + c) * 9 + kk];
  } else if (t < 46080) {
    int t2 = t - 36864;
    int j = t2 & 7, lane = (t2 >> 3) & 63, s = t2 >> 9;
    int km = lane & 15;
    int c = (s & 1) * 32 + ((lane >> 4) << 3) + j;
    int tap = s >> 1;
    float v = (km < 9) ? mw[(km * 64 + c) * 9 + tap] : 0.0f;
    wsb[t] = (_Float16)v;
  }
}

// ---------------------------------------------------------------------------
// Main fused kernel. 512 blocks x 512 threads (8 waves).
// Phase 1: vectorized staging on even-aligned float2 column pairs.
// Phase 3: wave = pixel row; fused sigmoid+coef epilogue.
// Phase 4: SPLIT-K (wave = px-group x sidx-half).
// Epilogue: EXCHANGE reduction — each wave dumps the half it won't finish
//           (32 KB in dead xs4 region), finishes the other; all 8 waves store.
// LDS: 44352 (xs, reused as 32 KB exchange buf) + 18432 (dynbuf) = 62784 B
// ---------------------------------------------------------------------------
__global__ __launch_bounds__(512, 4)
void deform_main(const float* __restrict__ x,
                 const float* __restrict__ ele,
                 const float* __restrict__ ow,
                 const float* __restrict__ ob,
                 const float* __restrict__ mb,
                 const _Float16* __restrict__ wsb,
                 float* __restrict__ out) {
  __shared__ uint4 xs4[RS * CS * 9];       // 44352 B, f16 data / exchange buf
  __shared__ uint4 dynbuf4[1152];          // 18432 B multi-use
  _Float16* offl = (_Float16*)dynbuf4;                       // 4608 B
  uint2* cwb = (uint2*)((char*)dynbuf4 + 4608);              // 9216 B
  unsigned* crc = (unsigned*)((char*)dynbuf4 + 4608 + 9216); // 4608 B
  f32x4* redbuf = (f32x4*)xs4;             // 32768 B, after phase 4

  const int tid = threadIdx.x;
  const int lane = tid & 63;
  const int wv = tid >> 6;        // 0..7
  const int pcl = lane & 15;      // MFMA col
  const int lq = lane >> 4;       // k-slice quadrant

  // XCD-bijective swizzle: consecutive decoded tiles land on the same XCD.
  const int bid = blockIdx.x;
  const int d = ((bid & 7) << 6) + (bid >> 3);   // 512 % 8 == 0 -> bijective
  const int b = d >> 7;
  const int t7 = d & 127;
  const int r0 = (t7 >> 3) * HT;   // 16 row-tiles
  const int c0 = (t7 & 7) * WT;    // 8 col-tiles

  // ---- Early: issue phase-2 ele loads (latency hidden under staging) -----
  float ev[9];
  {
    int tl = tid & 127;
    int pr = tl >> 4, pc = tl & 15;
    int h = r0 + pr, w = c0 + pc;
#pragma unroll
    for (int ty = 0; ty < 3; ++ty)
#pragma unroll
      for (int tx = 0; tx < 3; ++tx) {
        int gy = h - 1 + ty, gx = w - 1 + tx;
        float v = 0.0f;
        if ((unsigned)gy < 128u && (unsigned)gx < 128u)
          v = ele[b * (H_ * W_) + (gy << 7) + gx];
        ev[ty * 3 + tx] = v;
      }
  }

  // ---- Phase 1: stage x patch to LDS as f16 -------------------------------
  // Even-aligned float2 column pairs (fully in or fully out of [0,127]).
  {
    _Float16* xsb = (_Float16*)xs4;
    const int c2 = tid >> 4;               // 0..31 channel pair
    const int pl = tid & 15;
    const float* xb0 = x + b * (C_ * H_ * W_) + (2 * c2) * (H_ * W_);
    const float* xb1 = xb0 + (H_ * W_);
    for (int it = pl; it < 168; it += 16) {
      int row = (it * 5462) >> 16;         // it / 12 for it < 168
      int pc2 = it - row * 12;
      int gy = r0 - HALO + row;
      int gx = c0 - 4 + 2 * pc2;           // even
      float2 a = {0.0f, 0.0f}, bv = {0.0f, 0.0f};
      if ((unsigned)gy < 128u && (unsigned)gx < 127u) {
        int gi = (gy << 7) + gx;
        a = *(const float2*)(xb0 + gi);
        bv = *(const float2*)(xb1 + gi);
      }
      int cp = 2 * pc2 - 1;                // patch col of first px in pair
      int p = row * CS + cp;
      if (pc2 > 0) {
        half2v h0 = {(_Float16)a.x, (_Float16)bv.x};
        *(half2v*)(xsb + p * 72 + 2 * c2) = h0;
      }
      if (pc2 < 11) {
        half2v h1 = {(_Float16)a.y, (_Float16)bv.y};
        *(half2v*)(xsb + (p + 1) * 72 + 2 * c2) = h1;
      }
    }
  }

  // ---- Phase 2: offset conv (1->18ch 3x3), threads < 128, one px each ----
  if (tid < 128) {
#pragma unroll
    for (int ci = 0; ci < 18; ++ci) {
      float a = ob[ci];
#pragma unroll
      for (int tap = 0; tap < 9; ++tap) a += ev[tap] * ow[ci * 9 + tap];
      offl[tid * 18 + ci] = (_Float16)a;
    }
  }
  __syncthreads();   // xs + offl ready

  // ---- Phase 3: mask conv via f16 MFMA + FUSED sigmoid+coef epilogue -----
  {
    const half8* wfm8 = ((const half8*)wsb) + 4608;  // after 36864 f16
    f32x4 macc = {0.f, 0.f, 0.f, 0.f};
#pragma unroll
    for (int s = 0; s < 18; ++s) {
      const int tap = s >> 1;
      const int chalf = s & 1;
      const int ty = tap / 3, tx = tap - ty * 3;
      half8 aw = wfm8[s * 64 + lane];
      const int csl = chalf * 4 + lq;
      int rc = (wv + (HALO - 1) + ty) * CS + (pcl + (HALO - 1) + tx);
      half8 xv = *(const half8*)(xs4 + rc * 9 + csl);
      macc = __builtin_amdgcn_mfma_f32_16x16x32_f16(aw, xv, macc, 0, 0, 0);
    }
    // Fused epilogue: this lane owns (px, kk = lq*4 + r), exact cover of 0..8.
    const int px = wv * 16 + pcl;
    const int h = r0 + wv, w = c0 + pcl;
#pragma unroll
    for (int r = 0; r < 4; ++r) {
      int kk = lq * 4 + r;
      if (kk < 9) {
        float a = macc[r] + mb[kk];
        float m = 1.0f / (1.0f + __expf(-a));
        int ky = kk / 3 - 1;
        int kx = kk - (kk / 3) * 3 - 1;
        half2v o2 = *(const half2v*)&offl[px * 18 + kk * 2];
        float py = (float)(h + ky) + (float)o2[0];
        float pxx = (float)(w + kx) + (float)o2[1];
        float fy = floorf(py), fx = floorf(pxx);
        float wy = py - fy, wx = pxx - fx;
        int iy = (int)fy - r0 + HALO;
        int ix = (int)fx - c0 + HALO;
        int vy0 = (unsigned)iy < (unsigned)RS;
        int vy1 = (unsigned)(iy + 1) < (unsigned)RS;
        int vx0 = (unsigned)ix < (unsigned)CS;
        int vx1 = (unsigned)(ix + 1) < (unsigned)CS;
        int cy0 = min(max(iy, 0), RS - 1), cy1 = min(max(iy + 1, 0), RS - 1);
        int cx0 = min(max(ix, 0), CS - 1), cx1 = min(max(ix + 1, 0), CS - 1);
        float wy0 = 1.0f - wy, wx0 = 1.0f - wx;
        float a00 = wy0 * wx0 * m * (float)(vy0 & vx0);
        float a01 = wy0 * wx * m * (float)(vy0 & vx1);
        float a10 = wy * wx0 * m * (float)(vy1 & vx0);
        float a11 = wy * wx * m * (float)(vy1 & vx1);
        int rc00 = cy0 * CS + cx0;
        int drow = (cy1 - cy0) * CS;           // 0 or 22
        int dcol = cx1 - cx0;                  // 0 or 1
        uint2 cv;
        cv.x = pkh(a00, a01);
        cv.y = pkh(a10, a11);
        cwb[px * 9 + kk] = cv;
        crc[px * 9 + kk] =
            (unsigned)rc00 | ((unsigned)drow << 16) | ((unsigned)dcol << 24);
      }
    }
  }
  __syncthreads();   // coefficients ready

  // ---- Phase 4: split-K gather-blend + MFMA ------------------------------
  const half8* wf8 = (const half8*)wsb;
  const int pxg = wv & 3;        // pixel group: 32 px
  const int kh = wv >> 2;        // sidx half: 0 -> 0..8, 1 -> 9..17
  f32x4 acc[2][4];
#pragma unroll
  for (int pt = 0; pt < 2; ++pt)
#pragma unroll
    for (int ot = 0; ot < 4; ++ot) {
      f32x4 z = {0.f, 0.f, 0.f, 0.f};
      acc[pt][ot] = z;
    }

  const int pxA = pxg * 32 + pcl;        // pt = 0
  const int pxB = pxA + 16;              // pt = 1

#pragma unroll
  for (int s = 0; s < 9; ++s) {
    const int sidx = kh * 9 + s;
    const int kk = sidx >> 1;
    const int ch = sidx & 1;
    const int csl = ch * 4 + lq;
    half8 t[2];
#pragma unroll
    for (int pt = 0; pt < 2; ++pt) {
      const int px = pt ? pxB : pxA;
      uint2 cv = cwb[px * 9 + kk];
      unsigned rv = crc[px * 9 + kk];
      int rc00 = rv & 0xFFFF;
      int drow = (rv >> 16) & 0xFF;
      int dcol = rv >> 24;
      int rc01 = rc00 + dcol;
      int rc10 = rc00 + drow;
      int rc11 = rc10 + dcol;
      half2v c01 = __builtin_bit_cast(half2v, cv.x);
      half2v c23 = __builtin_bit_cast(half2v, cv.y);
      _Float16 a00 = c01[0], a01 = c01[1], a10 = c23[0], a11 = c23[1];
      half8 a00s = {a00, a00, a00, a00, a00, a00, a00, a00};
      half8 a01s = {a01, a01, a01, a01, a01, a01, a01, a01};
      half8 a10s = {a10, a10, a10, a10, a10, a10, a10, a10};
      half8 a11s = {a11, a11, a11, a11, a11, a11, a11, a11};
      half8 v00 = *(const half8*)(xs4 + rc00 * 9 + csl);
      half8 v01 = *(const half8*)(xs4 + rc01 * 9 + csl);
      half8 v10 = *(const half8*)(xs4 + rc10 * 9 + csl);
      half8 v11 = *(const half8*)(xs4 + rc11 * 9 + csl);
      t[pt] = v00 * a00s + v01 * a01s + v10 * a10s + v11 * a11s;
    }
#pragma unroll
    for (int ot = 0; ot < 4; ++ot) {
      half8 bw = wf8[(sidx * 4 + ot) * 64 + lane];
      acc[0][ot] = __builtin_amdgcn_mfma_f32_16x16x32_f16(bw, t[0], acc[0][ot], 0, 0, 0);
      acc[1][ot] = __builtin_amdgcn_mfma_f32_16x16x32_f16(bw, t[1], acc[1][ot], 0, 0, 0);
    }
  }

  __syncthreads();   // all waves done reading xs4/cwb/crc; xs4 reusable

  // ---- Exchange reduction: dump the half we won't finish ------------------
  // kh=0 dumps acc[pt=0], finishes pt=1;  kh=1 dumps acc[pt=1], finishes pt=0.
  {
    const int dumpPt = kh;            // kh=0 -> pt0, kh=1 -> pt1
#pragma unroll
    for (int ot = 0; ot < 4; ++ot)
      redbuf[(((kh * 4 + pxg) * 4 + ot) * 4 + lq) * 16 + pcl] = acc[dumpPt][ot];
  }
  __syncthreads();

  // ---- Symmetric epilogue: every wave completes one pt and stores ---------
  {
    const int myPt = kh ^ 1;          // kh=0 finishes pt1, kh=1 finishes pt0
    const int oKh = kh ^ 1;           // partner dumped acc[myPt]
    const int px = myPt ? pxB : pxA;
    const int h = r0 + (px >> 4);
    const int w = c0 + pcl;
#pragma unroll
    for (int ot = 0; ot < 4; ++ot) {
      f32x4 other = redbuf[(((oKh * 4 + pxg) * 4 + ot) * 4 + lq) * 16 + pcl];
#pragma unroll
      for (int r = 0; r < 4; ++r) {
        int o = ot * 16 + lq * 4 + r;
        float v = fmaxf(acc[myPt][ot][r] + other[r], 0.0f);
        out[((b * O_ + o) << 14) + (h << 7) + w] = v;
      }
    }
  }
}

extern "C" void kernel_launch(void* const* d_in, const int* in_sizes, int n_in,
                              void* d_out, int out_size, void* d_ws, size_t ws_size,
                              hipStream_t stream) {
  const float* x   = (const float*)d_in[0];
  const float* ele = (const float*)d_in[1];
  const float* ow  = (const float*)d_in[2];
  const float* ob  = (const float*)d_in[3];
  const float* mw  = (const float*)d_in[4];
  const float* mb  = (const float*)d_in[5];
  const float* dw  = (const float*)d_in[6];
  _Float16* wsb = (_Float16*)d_ws;

  build_frags<<<180, 256, 0, stream>>>(dw, mw, wsb);
  deform_main<<<512, 512, 0, stream>>>(x, ele, ow, ob, mb, wsb,
                                       (float*)d_out);
}

// Round 17
// 30.532 us; speedup vs baseline: 1.3952x; 1.3952x over previous
//
#include <hip/hip_runtime.h>
#include <hip/hip_bf16.h>
#include <hip/hip_fp16.h>

typedef _Float16 half8 __attribute__((ext_vector_type(8)));
typedef _Float16 half2v __attribute__((ext_vector_type(2)));
typedef float f32x4 __attribute__((ext_vector_type(4)));

#define B_ 4
#define C_ 64
#define O_ 64
#define H_ 128
#define W_ 128
#define HT 8     // tile rows
#define WT 16    // tile cols
#define HALO 3
#define RS 14    // staged rows (HT + 2*HALO)
#define CS 22    // staged cols (WT + 2*HALO)
// xs layout: [pixel][ch], pixel stride 72 f16 = 144B = 9 half8/uint4 slots

__device__ __forceinline__ unsigned pkh(float lo, float hi) {
  half2v v = {(_Float16)lo, (_Float16)hi};
  return __builtin_bit_cast(unsigned, v);
}

// ---------------------------------------------------------------------------
// Kernel 0: pre-build fragment-ready f16 weights in workspace.
//  wf  (deform_w): 18 k-steps x 4 o-tiles x 64 lanes x 8 = 36864 f16
//  wfm (mask_w padded to 16 rows): 18 k-steps x 64 lanes x 8 = 9216 f16
// ---------------------------------------------------------------------------
__global__ void build_frags(const float* __restrict__ dw,
                            const float* __restrict__ mw,
                            _Float16* __restrict__ wsb) {
  int t = blockIdx.x * 256 + threadIdx.x;
  if (t < 36864) {
    int j = t & 7, lane = (t >> 3) & 63, ot = (t >> 9) & 3, s = t >> 11;
    int kk = s >> 1, ch = s & 1;
    int o = ot * 16 + (lane & 15);
    int c = ch * 32 + ((lane >> 4) << 3) + j;
    wsb[t] = (_Float16)dw[(o * 64 + c) * 9 + kk];
  } else if (t < 46080) {
    int t2 = t - 36864;
    int j = t2 & 7, lane = (t2 >> 3) & 63, s = t2 >> 9;
    int km = lane & 15;
    int c = (s & 1) * 32 + ((lane >> 4) << 3) + j;
    int tap = s >> 1;
    float v = (km < 9) ? mw[(km * 64 + c) * 9 + tap] : 0.0f;
    wsb[t] = (_Float16)v;
  }
}

// ---------------------------------------------------------------------------
// Main fused kernel. 512 blocks x 512 threads (8 waves).
// Phase 1: vectorized staging on even-aligned float2 column pairs.
// Phase 3: wave = pixel row; fused sigmoid+coef epilogue.
// Phase 4: SPLIT-K (wave = px-group x sidx-half); two-pass LDS reduction.
// LDS: 44352 (xs) + 18432 (dynbuf: offl/cwb/crc, reused as redbuf) = 62784 B
// ---------------------------------------------------------------------------
__global__ __launch_bounds__(512, 4)
void deform_main(const float* __restrict__ x,
                 const float* __restrict__ ele,
                 const float* __restrict__ ow,
                 const float* __restrict__ ob,
                 const float* __restrict__ mb,
                 const _Float16* __restrict__ wsb,
                 float* __restrict__ out) {
  __shared__ uint4 xs4[RS * CS * 9];       // 44352 B, f16 data
  __shared__ uint4 dynbuf4[1152];          // 18432 B multi-use
  _Float16* offl = (_Float16*)dynbuf4;                       // 4608 B
  uint2* cwb = (uint2*)((char*)dynbuf4 + 4608);              // 9216 B
  unsigned* crc = (unsigned*)((char*)dynbuf4 + 4608 + 9216); // 4608 B
  f32x4* redbuf = (f32x4*)dynbuf4;         // 16384 B per pass, after phase 4

  const int tid = threadIdx.x;
  const int lane = tid & 63;
  const int wv = tid >> 6;        // 0..7
  const int pcl = lane & 15;      // MFMA col
  const int lq = lane >> 4;       // k-slice quadrant

  // XCD-bijective swizzle: consecutive decoded tiles land on the same XCD.
  const int bid = blockIdx.x;
  const int d = ((bid & 7) << 6) + (bid >> 3);   // 512 % 8 == 0 -> bijective
  const int b = d >> 7;
  const int t7 = d & 127;
  const int r0 = (t7 >> 3) * HT;   // 16 row-tiles
  const int c0 = (t7 & 7) * WT;    // 8 col-tiles

  // ---- Early: issue phase-2 ele loads (latency hidden under staging) -----
  float ev[9];
  {
    int tl = tid & 127;
    int pr = tl >> 4, pc = tl & 15;
    int h = r0 + pr, w = c0 + pc;
#pragma unroll
    for (int ty = 0; ty < 3; ++ty)
#pragma unroll
      for (int tx = 0; tx < 3; ++tx) {
        int gy = h - 1 + ty, gx = w - 1 + tx;
        float v = 0.0f;
        if ((unsigned)gy < 128u && (unsigned)gx < 128u)
          v = ele[b * (H_ * W_) + (gy << 7) + gx];
        ev[ty * 3 + tx] = v;
      }
  }

  // ---- Phase 1: stage x patch to LDS as f16 -------------------------------
  // Even-aligned float2 column pairs: item it = (row, pc2); pair covers
  // gx = c0-4+2*pc2, gx+1 (always even -> 8B-aligned float2; fully in or
  // fully out of [0,127], no partial case). 12 pairs x 14 rows = 168 items.
  {
    _Float16* xsb = (_Float16*)xs4;
    const int c2 = tid >> 4;               // 0..31 channel pair
    const int pl = tid & 15;
    const float* xb0 = x + b * (C_ * H_ * W_) + (2 * c2) * (H_ * W_);
    const float* xb1 = xb0 + (H_ * W_);
    for (int it = pl; it < 168; it += 16) {
      int row = (it * 5462) >> 16;         // it / 12 for it < 168
      int pc2 = it - row * 12;
      int gy = r0 - HALO + row;
      int gx = c0 - 4 + 2 * pc2;           // even
      float2 a = {0.0f, 0.0f}, bv = {0.0f, 0.0f};
      if ((unsigned)gy < 128u && (unsigned)gx < 127u) {
        int gi = (gy << 7) + gx;
        a = *(const float2*)(xb0 + gi);
        bv = *(const float2*)(xb1 + gi);
      }
      int cp = 2 * pc2 - 1;                // patch col of first px in pair
      int p = row * CS + cp;
      if (pc2 > 0) {
        half2v h0 = {(_Float16)a.x, (_Float16)bv.x};
        *(half2v*)(xsb + p * 72 + 2 * c2) = h0;
      }
      if (pc2 < 11) {
        half2v h1 = {(_Float16)a.y, (_Float16)bv.y};
        *(half2v*)(xsb + (p + 1) * 72 + 2 * c2) = h1;
      }
    }
  }

  // ---- Phase 2: offset conv (1->18ch 3x3), threads < 128, one px each ----
  if (tid < 128) {
#pragma unroll
    for (int ci = 0; ci < 18; ++ci) {
      float a = ob[ci];
#pragma unroll
      for (int tap = 0; tap < 9; ++tap) a += ev[tap] * ow[ci * 9 + tap];
      offl[tid * 18 + ci] = (_Float16)a;
    }
  }
  __syncthreads();   // xs + offl ready

  // ---- Phase 3: mask conv via f16 MFMA + FUSED sigmoid+coef epilogue -----
  {
    const half8* wfm8 = ((const half8*)wsb) + 4608;  // after 36864 f16
    f32x4 macc = {0.f, 0.f, 0.f, 0.f};
#pragma unroll
    for (int s = 0; s < 18; ++s) {
      const int tap = s >> 1;
      const int chalf = s & 1;
      const int ty = tap / 3, tx = tap - ty * 3;
      half8 aw = wfm8[s * 64 + lane];
      const int csl = chalf * 4 + lq;
      int rc = (wv + (HALO - 1) + ty) * CS + (pcl + (HALO - 1) + tx);
      half8 xv = *(const half8*)(xs4 + rc * 9 + csl);
      macc = __builtin_amdgcn_mfma_f32_16x16x32_f16(aw, xv, macc, 0, 0, 0);
    }
    // Fused epilogue: this lane owns (px, kk = lq*4 + r), exact cover of 0..8.
    const int px = wv * 16 + pcl;
    const int h = r0 + wv, w = c0 + pcl;
#pragma unroll
    for (int r = 0; r < 4; ++r) {
      int kk = lq * 4 + r;
      if (kk < 9) {
        float a = macc[r] + mb[kk];
        float m = 1.0f / (1.0f + __expf(-a));
        int ky = kk / 3 - 1;
        int kx = kk - (kk / 3) * 3 - 1;
        half2v o2 = *(const half2v*)&offl[px * 18 + kk * 2];
        float py = (float)(h + ky) + (float)o2[0];
        float pxx = (float)(w + kx) + (float)o2[1];
        float fy = floorf(py), fx = floorf(pxx);
        float wy = py - fy, wx = pxx - fx;
        int iy = (int)fy - r0 + HALO;
        int ix = (int)fx - c0 + HALO;
        int vy0 = (unsigned)iy < (unsigned)RS;
        int vy1 = (unsigned)(iy + 1) < (unsigned)RS;
        int vx0 = (unsigned)ix < (unsigned)CS;
        int vx1 = (unsigned)(ix + 1) < (unsigned)CS;
        int cy0 = min(max(iy, 0), RS - 1), cy1 = min(max(iy + 1, 0), RS - 1);
        int cx0 = min(max(ix, 0), CS - 1), cx1 = min(max(ix + 1, 0), CS - 1);
        float wy0 = 1.0f - wy, wx0 = 1.0f - wx;
        float a00 = wy0 * wx0 * m * (float)(vy0 & vx0);
        float a01 = wy0 * wx * m * (float)(vy0 & vx1);
        float a10 = wy * wx0 * m * (float)(vy1 & vx0);
        float a11 = wy * wx * m * (float)(vy1 & vx1);
        int rc00 = cy0 * CS + cx0;
        int drow = (cy1 - cy0) * CS;           // 0 or 22
        int dcol = cx1 - cx0;                  // 0 or 1
        uint2 cv;
        cv.x = pkh(a00, a01);
        cv.y = pkh(a10, a11);
        cwb[px * 9 + kk] = cv;
        crc[px * 9 + kk] =
            (unsigned)rc00 | ((unsigned)drow << 16) | ((unsigned)dcol << 24);
      }
    }
  }
  __syncthreads();   // coefficients ready

  // ---- Phase 4: split-K gather-blend + MFMA ------------------------------
  const half8* wf8 = (const half8*)wsb;
  const int pxg = wv & 3;        // pixel group: 32 px
  const int kh = wv >> 2;        // sidx half: 0 -> 0..8, 1 -> 9..17
  f32x4 acc[2][4];
#pragma unroll
  for (int pt = 0; pt < 2; ++pt)
#pragma unroll
    for (int ot = 0; ot < 4; ++ot) {
      f32x4 z = {0.f, 0.f, 0.f, 0.f};
      acc[pt][ot] = z;
    }

  const int pxA = pxg * 32 + pcl;        // pt = 0
  const int pxB = pxA + 16;              // pt = 1

#pragma unroll
  for (int s = 0; s < 9; ++s) {
    const int sidx = kh * 9 + s;
    const int kk = sidx >> 1;
    const int ch = sidx & 1;
    const int csl = ch * 4 + lq;
    half8 t[2];
#pragma unroll
    for (int pt = 0; pt < 2; ++pt) {
      const int px = pt ? pxB : pxA;
      uint2 cv = cwb[px * 9 + kk];
      unsigned rv = crc[px * 9 + kk];
      int rc00 = rv & 0xFFFF;
      int drow = (rv >> 16) & 0xFF;
      int dcol = rv >> 24;
      int rc01 = rc00 + dcol;
      int rc10 = rc00 + drow;
      int rc11 = rc10 + dcol;
      half2v c01 = __builtin_bit_cast(half2v, cv.x);
      half2v c23 = __builtin_bit_cast(half2v, cv.y);
      _Float16 a00 = c01[0], a01 = c01[1], a10 = c23[0], a11 = c23[1];
      half8 a00s = {a00, a00, a00, a00, a00, a00, a00, a00};
      half8 a01s = {a01, a01, a01, a01, a01, a01, a01, a01};
      half8 a10s = {a10, a10, a10, a10, a10, a10, a10, a10};
      half8 a11s = {a11, a11, a11, a11, a11, a11, a11, a11};
      half8 v00 = *(const half8*)(xs4 + rc00 * 9 + csl);
      half8 v01 = *(const half8*)(xs4 + rc01 * 9 + csl);
      half8 v10 = *(const half8*)(xs4 + rc10 * 9 + csl);
      half8 v11 = *(const half8*)(xs4 + rc11 * 9 + csl);
      t[pt] = v00 * a00s + v01 * a01s + v10 * a10s + v11 * a11s;
    }
#pragma unroll
    for (int ot = 0; ot < 4; ++ot) {
      half8 bw = wf8[(sidx * 4 + ot) * 64 + lane];
      acc[0][ot] = __builtin_amdgcn_mfma_f32_16x16x32_f16(bw, t[0], acc[0][ot], 0, 0, 0);
      acc[1][ot] = __builtin_amdgcn_mfma_f32_16x16x32_f16(bw, t[1], acc[1][ot], 0, 0, 0);
    }
  }

  __syncthreads();   // all waves done reading cwb/crc; dynbuf reusable

  // ---- Two-pass reduction + epilogue (16384 B redbuf per pass) -----------
#pragma unroll
  for (int pt = 0; pt < 2; ++pt) {
    if (kh == 1) {
#pragma unroll
      for (int ot = 0; ot < 4; ++ot)
        redbuf[((pxg * 4 + ot) * 4 + lq) * 16 + pcl] = acc[pt][ot];
    }
    __syncthreads();
    if (kh == 0) {
      const int px = pt ? pxB : pxA;
      const int h = r0 + (px >> 4);
      const int w = c0 + pcl;
#pragma unroll
      for (int ot = 0; ot < 4; ++ot) {
        f32x4 other = redbuf[((pxg * 4 + ot) * 4 + lq) * 16 + pcl];
#pragma unroll
        for (int r = 0; r < 4; ++r) {
          int o = ot * 16 + lq * 4 + r;
          float v = fmaxf(acc[pt][ot][r] + other[r], 0.0f);
          out[((b * O_ + o) << 14) + (h << 7) + w] = v;
        }
      }
    }
    __syncthreads();
  }
}

extern "C" void kernel_launch(void* const* d_in, const int* in_sizes, int n_in,
                              void* d_out, int out_size, void* d_ws, size_t ws_size,
                              hipStream_t stream) {
  const float* x   = (const float*)d_in[0];
  const float* ele = (const float*)d_in[1];
  const float* ow  = (const float*)d_in[2];
  const float* ob  = (const float*)d_in[3];
  const float* mw  = (const float*)d_in[4];
  const float* mb  = (const float*)d_in[5];
  const float* dw  = (const float*)d_in[6];
  _Float16* wsb = (_Float16*)d_ws;

  build_frags<<<180, 256, 0, stream>>>(dw, mw, wsb);
  deform_main<<<512, 512, 0, stream>>>(x, ele, ow, ob, mb, wsb,
                                       (float*)d_out);
}

// Round 18
// 30.362 us; speedup vs baseline: 1.4030x; 1.0056x over previous
//
#include <hip/hip_runtime.h>
#include <hip/hip_bf16.h>
#include <hip/hip_fp16.h>

typedef _Float16 half8 __attribute__((ext_vector_type(8)));
typedef _Float16 half2v __attribute__((ext_vector_type(2)));
typedef float f32x4 __attribute__((ext_vector_type(4)));

#define B_ 4
#define C_ 64
#define O_ 64
#define H_ 128
#define W_ 128
#define HT 8     // tile rows
#define WT 16    // tile cols
#define HALO 3
#define RS 14    // staged rows (HT + 2*HALO)
#define CS 22    // staged cols (WT + 2*HALO)
// xs layout: [pixel][ch], pixel stride 72 f16 = 144B = 9 half8/uint4 slots

__device__ __forceinline__ unsigned pkh(float lo, float hi) {
  half2v v = {(_Float16)lo, (_Float16)hi};
  return __builtin_bit_cast(unsigned, v);
}

// ---------------------------------------------------------------------------
// Kernel 0: pre-build fragment-ready f16 weights in workspace.
//  wf  (deform_w): 18 k-steps x 4 o-tiles x 64 lanes x 8 = 36864 f16
//  wfm (mask_w padded to 16 rows): 18 k-steps x 64 lanes x 8 = 9216 f16
// ---------------------------------------------------------------------------
__global__ void build_frags(const float* __restrict__ dw,
                            const float* __restrict__ mw,
                            _Float16* __restrict__ wsb) {
  int t = blockIdx.x * 256 + threadIdx.x;
  if (t < 36864) {
    int j = t & 7, lane = (t >> 3) & 63, ot = (t >> 9) & 3, s = t >> 11;
    int kk = s >> 1, ch = s & 1;
    int o = ot * 16 + (lane & 15);
    int c = ch * 32 + ((lane >> 4) << 3) + j;
    wsb[t] = (_Float16)dw[(o * 64 + c) * 9 + kk];
  } else if (t < 46080) {
    int t2 = t - 36864;
    int j = t2 & 7, lane = (t2 >> 3) & 63, s = t2 >> 9;
    int km = lane & 15;
    int c = (s & 1) * 32 + ((lane >> 4) << 3) + j;
    int tap = s >> 1;
    float v = (km < 9) ? mw[(km * 64 + c) * 9 + tap] : 0.0f;
    wsb[t] = (_Float16)v;
  }
}

// ---------------------------------------------------------------------------
// Main fused kernel. 512 blocks x 512 threads (8 waves).
// Phase 1: fully-unrolled staging — all 22 float2 loads issued before any
//          LDS write (T14 async-STAGE split); masked tail.
// Phase 3: wave = pixel row; fused sigmoid+coef epilogue.
// Phase 4: SPLIT-K (wave = px-group x sidx-half); two-pass LDS reduction.
// LDS: 44352 (xs) + 18432 (dynbuf: offl/cwb/crc, reused as redbuf) = 62784 B
// ---------------------------------------------------------------------------
__global__ __launch_bounds__(512, 4)
void deform_main(const float* __restrict__ x,
                 const float* __restrict__ ele,
                 const float* __restrict__ ow,
                 const float* __restrict__ ob,
                 const float* __restrict__ mb,
                 const _Float16* __restrict__ wsb,
                 float* __restrict__ out) {
  __shared__ uint4 xs4[RS * CS * 9];       // 44352 B, f16 data
  __shared__ uint4 dynbuf4[1152];          // 18432 B multi-use
  _Float16* offl = (_Float16*)dynbuf4;                       // 4608 B
  uint2* cwb = (uint2*)((char*)dynbuf4 + 4608);              // 9216 B
  unsigned* crc = (unsigned*)((char*)dynbuf4 + 4608 + 9216); // 4608 B
  f32x4* redbuf = (f32x4*)dynbuf4;         // 16384 B per pass, after phase 4

  const int tid = threadIdx.x;
  const int lane = tid & 63;
  const int wv = tid >> 6;        // 0..7
  const int pcl = lane & 15;      // MFMA col
  const int lq = lane >> 4;       // k-slice quadrant

  // XCD-bijective swizzle: consecutive decoded tiles land on the same XCD.
  const int bid = blockIdx.x;
  const int d = ((bid & 7) << 6) + (bid >> 3);   // 512 % 8 == 0 -> bijective
  const int b = d >> 7;
  const int t7 = d & 127;
  const int r0 = (t7 >> 3) * HT;   // 16 row-tiles
  const int c0 = (t7 & 7) * WT;    // 8 col-tiles

  // ---- Early: issue phase-2 ele loads (latency hidden under staging) -----
  float ev[9];
  {
    int tl = tid & 127;
    int pr = tl >> 4, pc = tl & 15;
    int h = r0 + pr, w = c0 + pc;
#pragma unroll
    for (int ty = 0; ty < 3; ++ty)
#pragma unroll
      for (int tx = 0; tx < 3; ++tx) {
        int gy = h - 1 + ty, gx = w - 1 + tx;
        float v = 0.0f;
        if ((unsigned)gy < 128u && (unsigned)gx < 128u)
          v = ele[b * (H_ * W_) + (gy << 7) + gx];
        ev[ty * 3 + tx] = v;
      }
  }

  // ---- Phase 1: stage x patch to LDS as f16 -------------------------------
  // Even-aligned float2 column pairs; FIXED 11 iterations, loads all issued
  // before any cvt/LDS-write (named registers, compile-time indexed).
  {
    _Float16* xsb = (_Float16*)xs4;
    const int c2 = tid >> 4;               // 0..31 channel pair
    const int pl = tid & 15;
    const float* xb0 = x + b * (C_ * H_ * W_) + (2 * c2) * (H_ * W_);
    const float* xb1 = xb0 + (H_ * W_);

    float2 va[11], vb[11];
#pragma unroll
    for (int k = 0; k < 11; ++k) {
      int it = pl + k * 16;                // 0..175
      int live = it < 168;
      int itc = live ? it : 167;           // clamp for address safety
      int row = (itc * 5462) >> 16;        // itc / 12
      int pc2 = itc - row * 12;
      int gy = r0 - HALO + row;
      int gx = c0 - 4 + 2 * pc2;           // even
      float2 a = {0.0f, 0.0f}, bv2 = {0.0f, 0.0f};
      if (live && (unsigned)gy < 128u && (unsigned)gx < 127u) {
        int gi = (gy << 7) + gx;
        a = *(const float2*)(xb0 + gi);
        bv2 = *(const float2*)(xb1 + gi);
      }
      va[k] = a;
      vb[k] = bv2;
    }
#pragma unroll
    for (int k = 0; k < 11; ++k) {
      int it = pl + k * 16;
      if (it < 168) {
        int row = (it * 5462) >> 16;
        int pc2 = it - row * 12;
        int p = row * CS + 2 * pc2 - 1;
        if (pc2 > 0) {
          half2v h0 = {(_Float16)va[k].x, (_Float16)vb[k].x};
          *(half2v*)(xsb + p * 72 + 2 * c2) = h0;
        }
        if (pc2 < 11) {
          half2v h1 = {(_Float16)va[k].y, (_Float16)vb[k].y};
          *(half2v*)(xsb + (p + 1) * 72 + 2 * c2) = h1;
        }
      }
    }
  }

  // ---- Phase 2: offset conv (1->18ch 3x3), threads < 128, one px each ----
  if (tid < 128) {
#pragma unroll
    for (int ci = 0; ci < 18; ++ci) {
      float a = ob[ci];
#pragma unroll
      for (int tap = 0; tap < 9; ++tap) a += ev[tap] * ow[ci * 9 + tap];
      offl[tid * 18 + ci] = (_Float16)a;
    }
  }
  __syncthreads();   // xs + offl ready

  // ---- Phase 3: mask conv via f16 MFMA + FUSED sigmoid+coef epilogue -----
  {
    const half8* wfm8 = ((const half8*)wsb) + 4608;  // after 36864 f16
    f32x4 macc = {0.f, 0.f, 0.f, 0.f};
#pragma unroll
    for (int s = 0; s < 18; ++s) {
      const int tap = s >> 1;
      const int chalf = s & 1;
      const int ty = tap / 3, tx = tap - ty * 3;
      half8 aw = wfm8[s * 64 + lane];
      const int csl = chalf * 4 + lq;
      int rc = (wv + (HALO - 1) + ty) * CS + (pcl + (HALO - 1) + tx);
      half8 xv = *(const half8*)(xs4 + rc * 9 + csl);
      macc = __builtin_amdgcn_mfma_f32_16x16x32_f16(aw, xv, macc, 0, 0, 0);
    }
    // Fused epilogue: this lane owns (px, kk = lq*4 + r), exact cover of 0..8.
    const int px = wv * 16 + pcl;
    const int h = r0 + wv, w = c0 + pcl;
#pragma unroll
    for (int r = 0; r < 4; ++r) {
      int kk = lq * 4 + r;
      if (kk < 9) {
        float a = macc[r] + mb[kk];
        float m = 1.0f / (1.0f + __expf(-a));
        int ky = kk / 3 - 1;
        int kx = kk - (kk / 3) * 3 - 1;
        half2v o2 = *(const half2v*)&offl[px * 18 + kk * 2];
        float py = (float)(h + ky) + (float)o2[0];
        float pxx = (float)(w + kx) + (float)o2[1];
        float fy = floorf(py), fx = floorf(pxx);
        float wy = py - fy, wx = pxx - fx;
        int iy = (int)fy - r0 + HALO;
        int ix = (int)fx - c0 + HALO;
        int vy0 = (unsigned)iy < (unsigned)RS;
        int vy1 = (unsigned)(iy + 1) < (unsigned)RS;
        int vx0 = (unsigned)ix < (unsigned)CS;
        int vx1 = (unsigned)(ix + 1) < (unsigned)CS;
        int cy0 = min(max(iy, 0), RS - 1), cy1 = min(max(iy + 1, 0), RS - 1);
        int cx0 = min(max(ix, 0), CS - 1), cx1 = min(max(ix + 1, 0), CS - 1);
        float wy0 = 1.0f - wy, wx0 = 1.0f - wx;
        float a00 = wy0 * wx0 * m * (float)(vy0 & vx0);
        float a01 = wy0 * wx * m * (float)(vy0 & vx1);
        float a10 = wy * wx0 * m * (float)(vy1 & vx0);
        float a11 = wy * wx * m * (float)(vy1 & vx1);
        int rc00 = cy0 * CS + cx0;
        int drow = (cy1 - cy0) * CS;           // 0 or 22
        int dcol = cx1 - cx0;                  // 0 or 1
        uint2 cv;
        cv.x = pkh(a00, a01);
        cv.y = pkh(a10, a11);
        cwb[px * 9 + kk] = cv;
        crc[px * 9 + kk] =
            (unsigned)rc00 | ((unsigned)drow << 16) | ((unsigned)dcol << 24);
      }
    }
  }
  __syncthreads();   // coefficients ready

  // ---- Phase 4: split-K gather-blend + MFMA ------------------------------
  const half8* wf8 = (const half8*)wsb;
  const int pxg = wv & 3;        // pixel group: 32 px
  const int kh = wv >> 2;        // sidx half: 0 -> 0..8, 1 -> 9..17
  f32x4 acc[2][4];
#pragma unroll
  for (int pt = 0; pt < 2; ++pt)
#pragma unroll
    for (int ot = 0; ot < 4; ++ot) {
      f32x4 z = {0.f, 0.f, 0.f, 0.f};
      acc[pt][ot] = z;
    }

  const int pxA = pxg * 32 + pcl;        // pt = 0
  const int pxB = pxA + 16;              // pt = 1

#pragma unroll
  for (int s = 0; s < 9; ++s) {
    const int sidx = kh * 9 + s;
    const int kk = sidx >> 1;
    const int ch = sidx & 1;
    const int csl = ch * 4 + lq;
    half8 t[2];
#pragma unroll
    for (int pt = 0; pt < 2; ++pt) {
      const int px = pt ? pxB : pxA;
      uint2 cv = cwb[px * 9 + kk];
      unsigned rv = crc[px * 9 + kk];
      int rc00 = rv & 0xFFFF;
      int drow = (rv >> 16) & 0xFF;
      int dcol = rv >> 24;
      int rc01 = rc00 + dcol;
      int rc10 = rc00 + drow;
      int rc11 = rc10 + dcol;
      half2v c01 = __builtin_bit_cast(half2v, cv.x);
      half2v c23 = __builtin_bit_cast(half2v, cv.y);
      _Float16 a00 = c01[0], a01 = c01[1], a10 = c23[0], a11 = c23[1];
      half8 a00s = {a00, a00, a00, a00, a00, a00, a00, a00};
      half8 a01s = {a01, a01, a01, a01, a01, a01, a01, a01};
      half8 a10s = {a10, a10, a10, a10, a10, a10, a10, a10};
      half8 a11s = {a11, a11, a11, a11, a11, a11, a11, a11};
      half8 v00 = *(const half8*)(xs4 + rc00 * 9 + csl);
      half8 v01 = *(const half8*)(xs4 + rc01 * 9 + csl);
      half8 v10 = *(const half8*)(xs4 + rc10 * 9 + csl);
      half8 v11 = *(const half8*)(xs4 + rc11 * 9 + csl);
      t[pt] = v00 * a00s + v01 * a01s + v10 * a10s + v11 * a11s;
    }
#pragma unroll
    for (int ot = 0; ot < 4; ++ot) {
      half8 bw = wf8[(sidx * 4 + ot) * 64 + lane];
      acc[0][ot] = __builtin_amdgcn_mfma_f32_16x16x32_f16(bw, t[0], acc[0][ot], 0, 0, 0);
      acc[1][ot] = __builtin_amdgcn_mfma_f32_16x16x32_f16(bw, t[1], acc[1][ot], 0, 0, 0);
    }
  }

  __syncthreads();   // all waves done reading cwb/crc; dynbuf reusable

  // ---- Two-pass reduction + epilogue (16384 B redbuf per pass) -----------
#pragma unroll
  for (int pt = 0; pt < 2; ++pt) {
    if (kh == 1) {
#pragma unroll
      for (int ot = 0; ot < 4; ++ot)
        redbuf[((pxg * 4 + ot) * 4 + lq) * 16 + pcl] = acc[pt][ot];
    }
    __syncthreads();
    if (kh == 0) {
      const int px = pt ? pxB : pxA;
      const int h = r0 + (px >> 4);
      const int w = c0 + pcl;
#pragma unroll
      for (int ot = 0; ot < 4; ++ot) {
        f32x4 other = redbuf[((pxg * 4 + ot) * 4 + lq) * 16 + pcl];
#pragma unroll
        for (int r = 0; r < 4; ++r) {
          int o = ot * 16 + lq * 4 + r;
          float v = fmaxf(acc[pt][ot][r] + other[r], 0.0f);
          out[((b * O_ + o) << 14) + (h << 7) + w] = v;
        }
      }
    }
    __syncthreads();
  }
}

extern "C" void kernel_launch(void* const* d_in, const int* in_sizes, int n_in,
                              void* d_out, int out_size, void* d_ws, size_t ws_size,
                              hipStream_t stream) {
  const float* x   = (const float*)d_in[0];
  const float* ele = (const float*)d_in[1];
  const float* ow  = (const float*)d_in[2];
  const float* ob  = (const float*)d_in[3];
  const float* mw  = (const float*)d_in[4];
  const float* mb  = (const float*)d_in[5];
  const float* dw  = (const float*)d_in[6];
  _Float16* wsb = (_Float16*)d_ws;

  build_frags<<<180, 256, 0, stream>>>(dw, mw, wsb);
  deform_main<<<512, 512, 0, stream>>>(x, ele, ow, ob, mb, wsb,
                                       (float*)d_out);
}

// Round 19
// 29.914 us; speedup vs baseline: 1.4241x; 1.0150x over previous
//
#include <hip/hip_runtime.h>
#include <hip/hip_bf16.h>
#include <hip/hip_fp16.h>

typedef _Float16 half8 __attribute__((ext_vector_type(8)));
typedef _Float16 half2v __attribute__((ext_vector_type(2)));
typedef float f32x4 __attribute__((ext_vector_type(4)));

#define B_ 4
#define C_ 64
#define O_ 64
#define H_ 128
#define W_ 128
#define HT 8     // tile rows
#define WT 16    // tile cols
#define HALO 3
#define RS 14    // staged rows (HT + 2*HALO)
#define CS 22    // staged cols (WT + 2*HALO)
// xs layout: [pixel][ch], pixel stride 72 f16 = 144B = 9 half8/uint4 slots

__device__ __forceinline__ unsigned pkh(float lo, float hi) {
  half2v v = {(_Float16)lo, (_Float16)hi};
  return __builtin_bit_cast(unsigned, v);
}

// ---------------------------------------------------------------------------
// Kernel 0: pre-build fragment-ready f16 weights in workspace.
//  wf  (deform_w): 18 k-steps x 4 o-tiles x 64 lanes x 8 = 36864 f16
//  wfm (mask_w padded to 16 rows): 18 k-steps x 64 lanes x 8 = 9216 f16
// ---------------------------------------------------------------------------
__global__ void build_frags(const float* __restrict__ dw,
                            const float* __restrict__ mw,
                            _Float16* __restrict__ wsb) {
  int t = blockIdx.x * 256 + threadIdx.x;
  if (t < 36864) {
    int j = t & 7, lane = (t >> 3) & 63, ot = (t >> 9) & 3, s = t >> 11;
    int kk = s >> 1, ch = s & 1;
    int o = ot * 16 + (lane & 15);
    int c = ch * 32 + ((lane >> 4) << 3) + j;
    wsb[t] = (_Float16)dw[(o * 64 + c) * 9 + kk];
  } else if (t < 46080) {
    int t2 = t - 36864;
    int j = t2 & 7, lane = (t2 >> 3) & 63, s = t2 >> 9;
    int km = lane & 15;
    int c = (s & 1) * 32 + ((lane >> 4) << 3) + j;
    int tap = s >> 1;
    float v = (km < 9) ? mw[(km * 64 + c) * 9 + tap] : 0.0f;
    wsb[t] = (_Float16)v;
  }
}

// ---------------------------------------------------------------------------
// Main fused kernel. 512 blocks x 512 threads (8 waves).
// Phase 1: fully-unrolled staging (loads issued before writes).
// Phase 3: wave = pixel row; fused sigmoid+coef epilogue.
// Phase 4: SPLIT-K (wave = px-group x sidx-half).
// Epilogue: symmetric single-pass exchange (literal acc indices, wave-uniform
//           kh branch); buffer in dead xs4 region; 4 barriers total.
// LDS: 44352 (xs / 32768 exchange) + 18432 (dynbuf) = 62784 B
// ---------------------------------------------------------------------------
__global__ __launch_bounds__(512, 4)
void deform_main(const float* __restrict__ x,
                 const float* __restrict__ ele,
                 const float* __restrict__ ow,
                 const float* __restrict__ ob,
                 const float* __restrict__ mb,
                 const _Float16* __restrict__ wsb,
                 float* __restrict__ out) {
  __shared__ uint4 xs4[RS * CS * 9];       // 44352 B, f16 data / exchange buf
  __shared__ uint4 dynbuf4[1152];          // 18432 B multi-use
  _Float16* offl = (_Float16*)dynbuf4;                       // 4608 B
  uint2* cwb = (uint2*)((char*)dynbuf4 + 4608);              // 9216 B
  unsigned* crc = (unsigned*)((char*)dynbuf4 + 4608 + 9216); // 4608 B
  f32x4* xbuf = (f32x4*)xs4;               // 32768 B exchange, after phase 4

  const int tid = threadIdx.x;
  const int lane = tid & 63;
  const int wv = tid >> 6;        // 0..7
  const int pcl = lane & 15;      // MFMA col
  const int lq = lane >> 4;       // k-slice quadrant

  // XCD-bijective swizzle: consecutive decoded tiles land on the same XCD.
  const int bid = blockIdx.x;
  const int d = ((bid & 7) << 6) + (bid >> 3);   // 512 % 8 == 0 -> bijective
  const int b = d >> 7;
  const int t7 = d & 127;
  const int r0 = (t7 >> 3) * HT;   // 16 row-tiles
  const int c0 = (t7 & 7) * WT;    // 8 col-tiles

  // ---- Early: issue phase-2 ele loads (latency hidden under staging) -----
  float ev[9];
  {
    int tl = tid & 127;
    int pr = tl >> 4, pc = tl & 15;
    int h = r0 + pr, w = c0 + pc;
#pragma unroll
    for (int ty = 0; ty < 3; ++ty)
#pragma unroll
      for (int tx = 0; tx < 3; ++tx) {
        int gy = h - 1 + ty, gx = w - 1 + tx;
        float v = 0.0f;
        if ((unsigned)gy < 128u && (unsigned)gx < 128u)
          v = ele[b * (H_ * W_) + (gy << 7) + gx];
        ev[ty * 3 + tx] = v;
      }
  }

  // ---- Phase 1: stage x patch to LDS as f16 -------------------------------
  // Even-aligned float2 column pairs; FIXED 11 iterations, loads all issued
  // before any cvt/LDS-write (named registers, compile-time indexed).
  {
    _Float16* xsb = (_Float16*)xs4;
    const int c2 = tid >> 4;               // 0..31 channel pair
    const int pl = tid & 15;
    const float* xb0 = x + b * (C_ * H_ * W_) + (2 * c2) * (H_ * W_);
    const float* xb1 = xb0 + (H_ * W_);

    float2 va[11], vb[11];
#pragma unroll
    for (int k = 0; k < 11; ++k) {
      int it = pl + k * 16;                // 0..175
      int live = it < 168;
      int itc = live ? it : 167;           // clamp for address safety
      int row = (itc * 5462) >> 16;        // itc / 12
      int pc2 = itc - row * 12;
      int gy = r0 - HALO + row;
      int gx = c0 - 4 + 2 * pc2;           // even
      float2 a = {0.0f, 0.0f}, bv2 = {0.0f, 0.0f};
      if (live && (unsigned)gy < 128u && (unsigned)gx < 127u) {
        int gi = (gy << 7) + gx;
        a = *(const float2*)(xb0 + gi);
        bv2 = *(const float2*)(xb1 + gi);
      }
      va[k] = a;
      vb[k] = bv2;
    }
#pragma unroll
    for (int k = 0; k < 11; ++k) {
      int it = pl + k * 16;
      if (it < 168) {
        int row = (it * 5462) >> 16;
        int pc2 = it - row * 12;
        int p = row * CS + 2 * pc2 - 1;
        if (pc2 > 0) {
          half2v h0 = {(_Float16)va[k].x, (_Float16)vb[k].x};
          *(half2v*)(xsb + p * 72 + 2 * c2) = h0;
        }
        if (pc2 < 11) {
          half2v h1 = {(_Float16)va[k].y, (_Float16)vb[k].y};
          *(half2v*)(xsb + (p + 1) * 72 + 2 * c2) = h1;
        }
      }
    }
  }

  // ---- Phase 2: offset conv (1->18ch 3x3), threads < 128, one px each ----
  if (tid < 128) {
#pragma unroll
    for (int ci = 0; ci < 18; ++ci) {
      float a = ob[ci];
#pragma unroll
      for (int tap = 0; tap < 9; ++tap) a += ev[tap] * ow[ci * 9 + tap];
      offl[tid * 18 + ci] = (_Float16)a;
    }
  }
  __syncthreads();   // xs + offl ready

  // ---- Phase 3: mask conv via f16 MFMA + FUSED sigmoid+coef epilogue -----
  {
    const half8* wfm8 = ((const half8*)wsb) + 4608;  // after 36864 f16
    f32x4 macc = {0.f, 0.f, 0.f, 0.f};
#pragma unroll
    for (int s = 0; s < 18; ++s) {
      const int tap = s >> 1;
      const int chalf = s & 1;
      const int ty = tap / 3, tx = tap - ty * 3;
      half8 aw = wfm8[s * 64 + lane];
      const int csl = chalf * 4 + lq;
      int rc = (wv + (HALO - 1) + ty) * CS + (pcl + (HALO - 1) + tx);
      half8 xv = *(const half8*)(xs4 + rc * 9 + csl);
      macc = __builtin_amdgcn_mfma_f32_16x16x32_f16(aw, xv, macc, 0, 0, 0);
    }
    // Fused epilogue: this lane owns (px, kk = lq*4 + r), exact cover of 0..8.
    const int px = wv * 16 + pcl;
    const int h = r0 + wv, w = c0 + pcl;
#pragma unroll
    for (int r = 0; r < 4; ++r) {
      int kk = lq * 4 + r;
      if (kk < 9) {
        float a = macc[r] + mb[kk];
        float m = 1.0f / (1.0f + __expf(-a));
        int ky = kk / 3 - 1;
        int kx = kk - (kk / 3) * 3 - 1;
        half2v o2 = *(const half2v*)&offl[px * 18 + kk * 2];
        float py = (float)(h + ky) + (float)o2[0];
        float pxx = (float)(w + kx) + (float)o2[1];
        float fy = floorf(py), fx = floorf(pxx);
        float wy = py - fy, wx = pxx - fx;
        int iy = (int)fy - r0 + HALO;
        int ix = (int)fx - c0 + HALO;
        int vy0 = (unsigned)iy < (unsigned)RS;
        int vy1 = (unsigned)(iy + 1) < (unsigned)RS;
        int vx0 = (unsigned)ix < (unsigned)CS;
        int vx1 = (unsigned)(ix + 1) < (unsigned)CS;
        int cy0 = min(max(iy, 0), RS - 1), cy1 = min(max(iy + 1, 0), RS - 1);
        int cx0 = min(max(ix, 0), CS - 1), cx1 = min(max(ix + 1, 0), CS - 1);
        float wy0 = 1.0f - wy, wx0 = 1.0f - wx;
        float a00 = wy0 * wx0 * m * (float)(vy0 & vx0);
        float a01 = wy0 * wx * m * (float)(vy0 & vx1);
        float a10 = wy * wx0 * m * (float)(vy1 & vx0);
        float a11 = wy * wx * m * (float)(vy1 & vx1);
        int rc00 = cy0 * CS + cx0;
        int drow = (cy1 - cy0) * CS;           // 0 or 22
        int dcol = cx1 - cx0;                  // 0 or 1
        uint2 cv;
        cv.x = pkh(a00, a01);
        cv.y = pkh(a10, a11);
        cwb[px * 9 + kk] = cv;
        crc[px * 9 + kk] =
            (unsigned)rc00 | ((unsigned)drow << 16) | ((unsigned)dcol << 24);
      }
    }
  }
  __syncthreads();   // coefficients ready

  // ---- Phase 4: split-K gather-blend + MFMA ------------------------------
  const half8* wf8 = (const half8*)wsb;
  const int pxg = wv & 3;        // pixel group: 32 px
  const int kh = wv >> 2;        // sidx half: 0 -> 0..8, 1 -> 9..17
  f32x4 acc[2][4];
#pragma unroll
  for (int pt = 0; pt < 2; ++pt)
#pragma unroll
    for (int ot = 0; ot < 4; ++ot) {
      f32x4 z = {0.f, 0.f, 0.f, 0.f};
      acc[pt][ot] = z;
    }

  const int pxA = pxg * 32 + pcl;        // pt = 0
  const int pxB = pxA + 16;              // pt = 1

#pragma unroll
  for (int s = 0; s < 9; ++s) {
    const int sidx = kh * 9 + s;
    const int kk = sidx >> 1;
    const int ch = sidx & 1;
    const int csl = ch * 4 + lq;
    half8 t[2];
#pragma unroll
    for (int pt = 0; pt < 2; ++pt) {
      const int px = pt ? pxB : pxA;
      uint2 cv = cwb[px * 9 + kk];
      unsigned rv = crc[px * 9 + kk];
      int rc00 = rv & 0xFFFF;
      int drow = (rv >> 16) & 0xFF;
      int dcol = rv >> 24;
      int rc01 = rc00 + dcol;
      int rc10 = rc00 + drow;
      int rc11 = rc10 + dcol;
      half2v c01 = __builtin_bit_cast(half2v, cv.x);
      half2v c23 = __builtin_bit_cast(half2v, cv.y);
      _Float16 a00 = c01[0], a01 = c01[1], a10 = c23[0], a11 = c23[1];
      half8 a00s = {a00, a00, a00, a00, a00, a00, a00, a00};
      half8 a01s = {a01, a01, a01, a01, a01, a01, a01, a01};
      half8 a10s = {a10, a10, a10, a10, a10, a10, a10, a10};
      half8 a11s = {a11, a11, a11, a11, a11, a11, a11, a11};
      half8 v00 = *(const half8*)(xs4 + rc00 * 9 + csl);
      half8 v01 = *(const half8*)(xs4 + rc01 * 9 + csl);
      half8 v10 = *(const half8*)(xs4 + rc10 * 9 + csl);
      half8 v11 = *(const half8*)(xs4 + rc11 * 9 + csl);
      t[pt] = v00 * a00s + v01 * a01s + v10 * a10s + v11 * a11s;
    }
#pragma unroll
    for (int ot = 0; ot < 4; ++ot) {
      half8 bw = wf8[(sidx * 4 + ot) * 64 + lane];
      acc[0][ot] = __builtin_amdgcn_mfma_f32_16x16x32_f16(bw, t[0], acc[0][ot], 0, 0, 0);
      acc[1][ot] = __builtin_amdgcn_mfma_f32_16x16x32_f16(bw, t[1], acc[1][ot], 0, 0, 0);
    }
  }

  __syncthreads();   // all waves done reading xs4/cwb/crc; xs4 reusable

  // ---- Symmetric single-pass exchange (literal acc indices) ---------------
  // kh=0 dumps acc[1] (pt1 partial), kh=1 dumps acc[0] (pt0 partial).
  // Partner wave = wv ^ 4 (same pxg, other K-half).
  if (kh == 0) {
#pragma unroll
    for (int ot = 0; ot < 4; ++ot)
      xbuf[(wv * 4 + ot) * 64 + lane] = acc[1][ot];
  } else {
#pragma unroll
    for (int ot = 0; ot < 4; ++ot)
      xbuf[(wv * 4 + ot) * 64 + lane] = acc[0][ot];
  }
  __syncthreads();

  {
    const int pw = wv ^ 4;
    if (kh == 0) {
      // finish pt=0: own acc[0] + partner's pt0 dump
      const int h = r0 + (pxA >> 4);
      const int w = c0 + pcl;
#pragma unroll
      for (int ot = 0; ot < 4; ++ot) {
        f32x4 other = xbuf[(pw * 4 + ot) * 64 + lane];
#pragma unroll
        for (int r = 0; r < 4; ++r) {
          int o = ot * 16 + lq * 4 + r;
          float v = fmaxf(acc[0][ot][r] + other[r], 0.0f);
          out[((b * O_ + o) << 14) + (h << 7) + w] = v;
        }
      }
    } else {
      // finish pt=1: own acc[1] + partner's pt1 dump
      const int h = r0 + (pxB >> 4);
      const int w = c0 + pcl;
#pragma unroll
      for (int ot = 0; ot < 4; ++ot) {
        f32x4 other = xbuf[(pw * 4 + ot) * 64 + lane];
#pragma unroll
        for (int r = 0; r < 4; ++r) {
          int o = ot * 16 + lq * 4 + r;
          float v = fmaxf(acc[1][ot][r] + other[r], 0.0f);
          out[((b * O_ + o) << 14) + (h << 7) + w] = v;
        }
      }
    }
  }
}

extern "C" void kernel_launch(void* const* d_in, const int* in_sizes, int n_in,
                              void* d_out, int out_size, void* d_ws, size_t ws_size,
                              hipStream_t stream) {
  const float* x   = (const float*)d_in[0];
  const float* ele = (const float*)d_in[1];
  const float* ow  = (const float*)d_in[2];
  const float* ob  = (const float*)d_in[3];
  const float* mw  = (const float*)d_in[4];
  const float* mb  = (const float*)d_in[5];
  const float* dw  = (const float*)d_in[6];
  _Float16* wsb = (_Float16*)d_ws;

  build_frags<<<180, 256, 0, stream>>>(dw, mw, wsb);
  deform_main<<<512, 512, 0, stream>>>(x, ele, ow, ob, mb, wsb,
                                       (float*)d_out);
}